// Round 9
// baseline (116.937 us; speedup 1.0000x reference)
//
#include <hip/hip_runtime.h>
#include <hip/hip_bf16.h>
#include <hip/hip_cooperative_groups.h>
#include <math.h>

namespace cg = cooperative_groups;

// Problem constants
#define BATCH 4
#define TLEN 8192
#define BT 32768      // BATCH*TLEN
#define DIM 512
#define CHUNK 128     // t per chunk
#define NCHUNK 64     // TLEN / CHUNK

// score GEMM tile
#define BM 128
#define BN 128
#define BK 32

typedef _Float16 h8 __attribute__((ext_vector_type(8)));
typedef _Float16 h4 __attribute__((ext_vector_type(4)));
typedef _Float16 h2 __attribute__((ext_vector_type(2)));
typedef float f4 __attribute__((ext_vector_type(4)));

__device__ __forceinline__ void gload_lds16(const _Float16* g, _Float16* l) {
    __builtin_amdgcn_global_load_lds(
        (const __attribute__((address_space(1))) void*)g,
        (__attribute__((address_space(3))) void*)l, 16, 0, 0);
}

// fast tanh: 1 - 2/(e^{2z}+1). |err| ~1e-6; saturates correctly at +-1.
__device__ __forceinline__ float fast_tanh(float z) {
    float u = __expf(2.0f * z);
    return 1.0f - __fdividef(2.0f, u + 1.0f);
}

// ---------------------------------------------------------------------------
// Kernel 0: convert x (fp32) and W1 (fp32) to fp16, packed into d_out scratch.
// ---------------------------------------------------------------------------
__global__ __launch_bounds__(256) void convert_kernel(
    const float* __restrict__ x, const float* __restrict__ W1,
    _Float16* __restrict__ hbuf)
{
    const long i = (long)blockIdx.x * 256 + threadIdx.x;   // float4 index
    const long XD4 = (long)BT * DIM / 4;
    const long total4 = XD4 + (long)DIM * DIM / 4;
    if (i >= total4) return;
    float4 v;
    if (i < XD4) v = ((const float4*)x)[i];
    else         v = ((const float4*)W1)[i - XD4];
    h4 o = { (_Float16)v.x, (_Float16)v.y, (_Float16)v.z, (_Float16)v.w };
    *(h4*)(hbuf + i * 4) = o;
}

// ---------------------------------------------------------------------------
// Kernel 1: score GEMM (R5-benched version: 2-buffer counted-vmcnt pipeline).
// Per K-step: STAGE(s+1) -> vmcnt(4) -> barrier -> ds_read+MFMA ->
// lgkmcnt(0) -> barrier.
// ---------------------------------------------------------------------------
__global__ __launch_bounds__(256, 4) void score_mfma_kernel(
    const _Float16* __restrict__ xh, const _Float16* __restrict__ wh,
    const float* __restrict__ b1, const float* __restrict__ w2,
    float* __restrict__ spart)
{
    __shared__ _Float16 Als[2][BM * BK];   // 2 x 8 KB
    __shared__ _Float16 Bls[2][BM * BK];   // 2 x 8 KB
    __shared__ float sred[2][BM];          // 1 KB

    // bijective XCD-chunked swizzle over 1024 blocks (1024 % 8 == 0)
    const int orig = blockIdx.x;
    const int wid  = (orig & 7) * 128 + (orig >> 3);
    const int bt = wid >> 2, be = wid & 3;
    const long trow0 = (long)bt * BM;
    const int  ecol0 = be * BN;

    const int tid  = threadIdx.x;
    const int lane = tid & 63;
    const int w    = tid >> 6;       // 0..3
    const int wr   = w >> 1;         // t-half of tile
    const int wc   = w & 1;          // e-half of tile
    const int l15  = lane & 15;
    const int lg   = lane >> 4;      // 0..3

    // staging: wave w covers rows [w*32, w*32+32), 8 rows per 1KB issue pair.
    // source 16B-group = (lane&3) ^ (srow&3)  (involution; read applies same)
    const int srow = w * 32 + (lane >> 2);
    const int skof = ((lane & 3) ^ (srow & 3)) * 8;
    const _Float16* ga = xh + (trow0 + srow) * DIM + skof;
    const _Float16* gb = wh + (long)(ecol0 + srow) * DIM + skof;
    _Float16* laA0 = &Als[0][w * 1024];
    _Float16* laB0 = &Bls[0][w * 1024];
    _Float16* laA1 = &Als[1][w * 1024];
    _Float16* laB1 = &Bls[1][w * 1024];

    // frag-read swizzled k-offset: constant per lane (row&3 == l15&3)
    const int koff = (lg ^ (l15 & 3)) * 8;

    // preload epilogue operands BEFORE the pipeline so loop vmcnt is exact
    float b1v[4], w2v[4];
    #pragma unroll
    for (int n = 0; n < 4; ++n) {
        int e = ecol0 + wc * 64 + n * 16 + l15;
        b1v[n] = b1[e];
        w2v[n] = w2[e];
    }
    asm volatile("s_waitcnt vmcnt(0)" ::: "memory");

    f4 acc[4][4];
    #pragma unroll
    for (int m = 0; m < 4; ++m)
        #pragma unroll
        for (int n = 0; n < 4; ++n) acc[m][n] = (f4){0.f, 0.f, 0.f, 0.f};

#define STAGE(A_, B_, k0_) {                         \
    gload_lds16(ga + (k0_),            (A_));        \
    gload_lds16(ga + 16 * DIM + (k0_), (A_) + 512);  \
    gload_lds16(gb + (k0_),            (B_));        \
    gload_lds16(gb + 16 * DIM + (k0_), (B_) + 512);  }

#define COMPUTE(bsel_) {                                                      \
    h8 afr[4], bfr[4];                                                        \
    _Pragma("unroll")                                                         \
    for (int m = 0; m < 4; ++m)                                               \
        afr[m] = *(const h8*)&Als[bsel_][(wr * 64 + m * 16 + l15) * BK + koff]; \
    _Pragma("unroll")                                                         \
    for (int n = 0; n < 4; ++n)                                               \
        bfr[n] = *(const h8*)&Bls[bsel_][(wc * 64 + n * 16 + l15) * BK + koff]; \
    _Pragma("unroll")                                                         \
    for (int m = 0; m < 4; ++m)                                               \
        _Pragma("unroll")                                                     \
        for (int n = 0; n < 4; ++n)                                           \
            acc[m][n] = __builtin_amdgcn_mfma_f32_16x16x32_f16(               \
                afr[m], bfr[n], acc[m][n], 0, 0, 0);                          }

    STAGE(laA0, laB0, 0);                          // stage 0 in flight (4)
    #pragma unroll 2
    for (int s = 0; s < 15; ++s) {
        // issue stage s+1 -> 8 outstanding; vmcnt(4) waits only stage s
        if (s & 1) { STAGE(laA0, laB0, (s + 1) * BK); }
        else       { STAGE(laA1, laB1, (s + 1) * BK); }
        asm volatile("s_waitcnt vmcnt(4)" ::: "memory");
        __builtin_amdgcn_s_barrier();
        if (s & 1) { COMPUTE(1); } else { COMPUTE(0); }
        asm volatile("s_waitcnt lgkmcnt(0)" ::: "memory");  // reads done
        __builtin_amdgcn_s_barrier();              // buffer s&1 now restageable
    }
    asm volatile("s_waitcnt vmcnt(0)" ::: "memory");   // drain stage 15
    __builtin_amdgcn_s_barrier();
    COMPUTE(1);                                    // s=15 -> buffer 1

    // epilogue: p = sum over this lane's 4 e's of w2*tanh(h + b1)
    float pp[4][4];
    #pragma unroll
    for (int m = 0; m < 4; ++m)
        #pragma unroll
        for (int i = 0; i < 4; ++i) {
            float p = 0.f;
            #pragma unroll
            for (int n = 0; n < 4; ++n)
                p += w2v[n] * fast_tanh(acc[m][n][i] + b1v[n]);
            pp[m][i] = p;
        }
    // reduce across the 16 e-lanes of each lane-group
    #pragma unroll
    for (int off = 1; off < 16; off <<= 1)
        #pragma unroll
        for (int m = 0; m < 4; ++m)
            #pragma unroll
            for (int i = 0; i < 4; ++i)
                pp[m][i] += __shfl_xor(pp[m][i], off);
    __syncthreads();
    if (l15 == 0) {
        #pragma unroll
        for (int m = 0; m < 4; ++m)
            #pragma unroll
            for (int i = 0; i < 4; ++i)
                sred[wc][wr * 64 + m * 16 + lg * 4 + i] = pp[m][i];
    }
    __syncthreads();
    if (tid < BM)
        spart[(long)be * BT + trow0 + tid] = sred[0][tid] + sred[1][tid];
}

// ---------------------------------------------------------------------------
// Kernel 2 (cooperative, 256 blocks x 256 threads, 1 block/CU @ 128.5 KB LDS):
// P1: stage fp16 x-chunk (128x512) into LDS; e[t]=exp(s[t]) into LDS;
//     csum[b,c,:] = sum_t e[t]*x[t,:] and esum[b,c] -> ws.
// grid.sync()
// P2: per-block exclusive prefixes: accX[d] = sum_{c'<c} csum[b,c',d],
//     den = sum_{c'<c} esum[b,c']  (redundant parallel reads, no scan kernel).
// P3: stream: acc += e[t]*x_lds[t,:]; den += e[t]; out[t,:] = acc/den.
// No global max: softmax shift-invariant, |s| <= ||w2||_1 ~ 28 (no overflow).
// ---------------------------------------------------------------------------
__global__ __launch_bounds__(256, 1) void fused_context_kernel(
    const _Float16* __restrict__ xh, const float* __restrict__ spart,
    float* __restrict__ csum, float* __restrict__ esum,
    float* __restrict__ out)
{
    __shared__ _Float16 xls[CHUNK * DIM];   // 128 KB
    __shared__ float el[CHUNK];             // 512 B
    __shared__ float wred[2];

    cg::grid_group grid = cg::this_grid();

    const int bid = blockIdx.x;
    const int c = bid & (NCHUNK - 1);
    const int b = bid >> 6;
    const int tid = threadIdx.x;
    const long rowbase = (long)b * TLEN + c * CHUNK;

    // ---- P1a: e[t] for this chunk (threads 0..127) ----
    if (tid < CHUNK) {
        const long bt = rowbase + tid;
        float sv = spart[bt] + spart[BT + bt]
                 + spart[2l * BT + bt] + spart[3l * BT + bt];
        float ev = __expf(sv);
        el[tid] = ev;
        float r = ev;
        #pragma unroll
        for (int off = 1; off < 64; off <<= 1) r += __shfl_xor(r, off);
        if ((tid & 63) == 0) wred[tid >> 6] = r;
    }

    // ---- P1b: stage x chunk into LDS (flat, coalesced h8) ----
    {
        const h8* g = (const h8*)(xh + rowbase * DIM);
        h8* l = (h8*)xls;
        #pragma unroll
        for (int k = 0; k < (CHUNK * DIM / 8) / 256; ++k)
            l[tid + k * 256] = g[tid + k * 256];
    }
    __syncthreads();
    if (tid == 0) esum[bid] = wred[0] + wred[1];

    // ---- P1c: csum for this chunk: thread owns d = {2tid, 2tid+1} ----
    float c0 = 0.f, c1 = 0.f;
    #pragma unroll 8
    for (int t = 0; t < CHUNK; ++t) {
        h2 xv = *(const h2*)&xls[t * DIM + tid * 2];
        float w = el[t];
        c0 += w * (float)xv[0];
        c1 += w * (float)xv[1];
    }
    *(float2*)&csum[(long)bid * DIM + tid * 2] = make_float2(c0, c1);

    grid.sync();

    // ---- P2: exclusive prefixes over chunks c' < c (redundant per block) ----
    float a0 = 0.f, a1 = 0.f, den = 0.f;
    for (int cp = 0; cp < c; ++cp) {
        float2 v = *(const float2*)&csum[(long)(b * NCHUNK + cp) * DIM + tid * 2];
        a0 += v.x;
        a1 += v.y;
    }
    #pragma unroll 8
    for (int cp = 0; cp < NCHUNK; ++cp) {
        float v = esum[b * NCHUNK + cp];
        den += (cp < c) ? v : 0.f;
    }

    // ---- P3: stream output rows from LDS ----
    float* ob = out + rowbase * DIM;
    for (int t = 0; t < CHUNK; ++t) {
        h2 xv = *(const h2*)&xls[t * DIM + tid * 2];
        float w = el[t];
        den += w;
        a0 += w * (float)xv[0];
        a1 += w * (float)xv[1];
        float inv = __fdividef(1.0f, den);
        *(float2*)&ob[(long)t * DIM + tid * 2] = make_float2(a0 * inv, a1 * inv);
    }
}

// ---------------------------------------------------------------------------
extern "C" void kernel_launch(void* const* d_in, const int* in_sizes, int n_in,
                              void* d_out, int out_size, void* d_ws, size_t ws_size,
                              hipStream_t stream)
{
    const float* x  = (const float*)d_in[0];   // [4,8192,512]
    const float* W1 = (const float*)d_in[1];   // [512,512] row-major [e][d]
    const float* b1 = (const float*)d_in[2];   // [512]
    const float* w2 = (const float*)d_in[3];   // [512]
    // d_in[4] = b2 scalar: softmax shift-invariant, unused.
    float* out = (float*)d_out;

    float* ws   = (float*)d_ws;
    float* csum = ws;                       // [4*64*512] = 131072 floats
    float* esum = ws + 4 * NCHUNK * DIM;    // [256]

    // fp16 operands + spart live in d_out (67 MB): xh consumed from LDS copies
    // before P3's out-writes clobber it; spart consumed in P1.
    _Float16* hbuf = (_Float16*)d_out;
    const _Float16* xh = hbuf;                              // 16.7M halfs
    const _Float16* wh = hbuf + (long)BT * DIM;             // 262K halfs
    float* spart = (float*)(hbuf + (long)BT * DIM + DIM * DIM);  // [4][32768]

    const long total4 = ((long)BT * DIM + (long)DIM * DIM) / 4;
    const int convBlocks = (int)((total4 + 255) / 256);

    convert_kernel<<<convBlocks, 256, 0, stream>>>(x, W1, hbuf);
    score_mfma_kernel<<<(BT / BM) * 4, 256, 0, stream>>>(xh, wh, b1, w2, spart);

    const _Float16* xh_c = xh;
    const float* spart_c = spart;
    void* args[] = { (void*)&xh_c, (void*)&spart_c, (void*)&csum,
                     (void*)&esum, (void*)&out };
    hipLaunchCooperativeKernel((const void*)fused_context_kernel,
                               dim3(NCHUNK * BATCH), dim3(256), args, 0, stream);
}

// Round 10
// 89.322 us; speedup vs baseline: 1.3092x; 1.3092x over previous
//
#include <hip/hip_runtime.h>
#include <hip/hip_bf16.h>
#include <math.h>

// Problem constants
#define BATCH 4
#define TLEN 8192
#define BT 32768      // BATCH*TLEN
#define DIM 512
#define CHUNK 128     // t per chunk
#define NCHUNK 64     // TLEN / CHUNK

// score GEMM tile
#define BM 128
#define BN 128
#define BK 32

typedef _Float16 h8 __attribute__((ext_vector_type(8)));
typedef _Float16 h4 __attribute__((ext_vector_type(4)));
typedef float f4 __attribute__((ext_vector_type(4)));

__device__ __forceinline__ void gload_lds16(const _Float16* g, _Float16* l) {
    __builtin_amdgcn_global_load_lds(
        (const __attribute__((address_space(1))) void*)g,
        (__attribute__((address_space(3))) void*)l, 16, 0, 0);
}

// fast tanh: 1 - 2/(e^{2z}+1). |err| ~1e-6; saturates correctly at +-1.
__device__ __forceinline__ float fast_tanh(float z) {
    float u = __expf(2.0f * z);
    return 1.0f - __fdividef(2.0f, u + 1.0f);
}

// ---------------------------------------------------------------------------
// Kernel 0: convert x (fp32) and W1 (fp32) to fp16 into the given buffers.
// ---------------------------------------------------------------------------
__global__ __launch_bounds__(256) void convert_kernel(
    const float* __restrict__ x, const float* __restrict__ W1,
    _Float16* __restrict__ xh, _Float16* __restrict__ wh)
{
    const long i = (long)blockIdx.x * 256 + threadIdx.x;   // float4 index
    const long XD4 = (long)BT * DIM / 4;
    const long total4 = XD4 + (long)DIM * DIM / 4;
    if (i >= total4) return;
    float4 v;
    _Float16* dst;
    long j;
    if (i < XD4) { v = ((const float4*)x)[i];        dst = xh; j = i; }
    else         { v = ((const float4*)W1)[i - XD4]; dst = wh; j = i - XD4; }
    h4 o = { (_Float16)v.x, (_Float16)v.y, (_Float16)v.z, (_Float16)v.w };
    *(h4*)(dst + j * 4) = o;
}

// ---------------------------------------------------------------------------
// Kernel 1: score GEMM (R5-benched: 2-buffer counted-vmcnt pipeline).
// Per K-step: STAGE(s+1) -> vmcnt(4) -> barrier -> ds_read+MFMA ->
// lgkmcnt(0) -> barrier.
// ---------------------------------------------------------------------------
__global__ __launch_bounds__(256, 4) void score_mfma_kernel(
    const _Float16* __restrict__ xh, const _Float16* __restrict__ wh,
    const float* __restrict__ b1, const float* __restrict__ w2,
    float* __restrict__ spart)
{
    __shared__ _Float16 Als[2][BM * BK];   // 2 x 8 KB
    __shared__ _Float16 Bls[2][BM * BK];   // 2 x 8 KB
    __shared__ float sred[2][BM];          // 1 KB

    // bijective XCD-chunked swizzle over 1024 blocks (1024 % 8 == 0)
    const int orig = blockIdx.x;
    const int wid  = (orig & 7) * 128 + (orig >> 3);
    const int bt = wid >> 2, be = wid & 3;
    const long trow0 = (long)bt * BM;
    const int  ecol0 = be * BN;

    const int tid  = threadIdx.x;
    const int lane = tid & 63;
    const int w    = tid >> 6;       // 0..3
    const int wr   = w >> 1;         // t-half of tile
    const int wc   = w & 1;          // e-half of tile
    const int l15  = lane & 15;
    const int lg   = lane >> 4;      // 0..3

    // staging: wave w covers rows [w*32, w*32+32), 8 rows per 1KB issue pair.
    // source 16B-group = (lane&3) ^ (srow&3)  (involution; read applies same)
    const int srow = w * 32 + (lane >> 2);
    const int skof = ((lane & 3) ^ (srow & 3)) * 8;
    const _Float16* ga = xh + (trow0 + srow) * DIM + skof;
    const _Float16* gb = wh + (long)(ecol0 + srow) * DIM + skof;
    _Float16* laA0 = &Als[0][w * 1024];
    _Float16* laB0 = &Bls[0][w * 1024];
    _Float16* laA1 = &Als[1][w * 1024];
    _Float16* laB1 = &Bls[1][w * 1024];

    // frag-read swizzled k-offset: constant per lane (row&3 == l15&3)
    const int koff = (lg ^ (l15 & 3)) * 8;

    // preload epilogue operands BEFORE the pipeline so loop vmcnt is exact
    float b1v[4], w2v[4];
    #pragma unroll
    for (int n = 0; n < 4; ++n) {
        int e = ecol0 + wc * 64 + n * 16 + l15;
        b1v[n] = b1[e];
        w2v[n] = w2[e];
    }
    asm volatile("s_waitcnt vmcnt(0)" ::: "memory");

    f4 acc[4][4];
    #pragma unroll
    for (int m = 0; m < 4; ++m)
        #pragma unroll
        for (int n = 0; n < 4; ++n) acc[m][n] = (f4){0.f, 0.f, 0.f, 0.f};

#define STAGE(A_, B_, k0_) {                         \
    gload_lds16(ga + (k0_),            (A_));        \
    gload_lds16(ga + 16 * DIM + (k0_), (A_) + 512);  \
    gload_lds16(gb + (k0_),            (B_));        \
    gload_lds16(gb + 16 * DIM + (k0_), (B_) + 512);  }

#define COMPUTE(bsel_) {                                                      \
    h8 afr[4], bfr[4];                                                        \
    _Pragma("unroll")                                                         \
    for (int m = 0; m < 4; ++m)                                               \
        afr[m] = *(const h8*)&Als[bsel_][(wr * 64 + m * 16 + l15) * BK + koff]; \
    _Pragma("unroll")                                                         \
    for (int n = 0; n < 4; ++n)                                               \
        bfr[n] = *(const h8*)&Bls[bsel_][(wc * 64 + n * 16 + l15) * BK + koff]; \
    _Pragma("unroll")                                                         \
    for (int m = 0; m < 4; ++m)                                               \
        _Pragma("unroll")                                                     \
        for (int n = 0; n < 4; ++n)                                           \
            acc[m][n] = __builtin_amdgcn_mfma_f32_16x16x32_f16(               \
                afr[m], bfr[n], acc[m][n], 0, 0, 0);                          }

    STAGE(laA0, laB0, 0);                          // stage 0 in flight (4)
    #pragma unroll 2
    for (int s = 0; s < 15; ++s) {
        // issue stage s+1 -> 8 outstanding; vmcnt(4) waits only stage s
        if (s & 1) { STAGE(laA0, laB0, (s + 1) * BK); }
        else       { STAGE(laA1, laB1, (s + 1) * BK); }
        asm volatile("s_waitcnt vmcnt(4)" ::: "memory");
        __builtin_amdgcn_s_barrier();
        if (s & 1) { COMPUTE(1); } else { COMPUTE(0); }
        asm volatile("s_waitcnt lgkmcnt(0)" ::: "memory");  // reads done
        __builtin_amdgcn_s_barrier();              // buffer s&1 now restageable
    }
    asm volatile("s_waitcnt vmcnt(0)" ::: "memory");   // drain stage 15
    __builtin_amdgcn_s_barrier();
    COMPUTE(1);                                    // s=15 -> buffer 1

    // epilogue: p = sum over this lane's 4 e's of w2*tanh(h + b1)
    float pp[4][4];
    #pragma unroll
    for (int m = 0; m < 4; ++m)
        #pragma unroll
        for (int i = 0; i < 4; ++i) {
            float p = 0.f;
            #pragma unroll
            for (int n = 0; n < 4; ++n)
                p += w2v[n] * fast_tanh(acc[m][n][i] + b1v[n]);
            pp[m][i] = p;
        }
    // reduce across the 16 e-lanes of each lane-group
    #pragma unroll
    for (int off = 1; off < 16; off <<= 1)
        #pragma unroll
        for (int m = 0; m < 4; ++m)
            #pragma unroll
            for (int i = 0; i < 4; ++i)
                pp[m][i] += __shfl_xor(pp[m][i], off);
    __syncthreads();
    if (l15 == 0) {
        #pragma unroll
        for (int m = 0; m < 4; ++m)
            #pragma unroll
            for (int i = 0; i < 4; ++i)
                sred[wc][wr * 64 + m * 16 + lg * 4 + i] = pp[m][i];
    }
    __syncthreads();
    if (tid < BM)
        spart[(long)be * BT + trow0 + tid] = sred[0][tid] + sred[1][tid];
}

// ---------------------------------------------------------------------------
// Kernel 2: chunk_sum. No global max needed (softmax shift-invariant; |s| is
// bounded by ||w2||_1 ~ 28 so exp(s) can't overflow fp32).
// Per (c,b) block: s[t] = sum_be spart[be][t] (-> ws for context),
// e[t] = exp(s[t]); csum[b,c,d] = sum_t e[t]*xh[t,d]; esum[b,c] = sum_t e[t].
// ---------------------------------------------------------------------------
__global__ __launch_bounds__(128) void chunk_sum_kernel(
    const _Float16* __restrict__ xh, const float* __restrict__ spart,
    float* __restrict__ s_ws, float* __restrict__ csum,
    float* __restrict__ esum)
{
    __shared__ float el[CHUNK];
    __shared__ float wred[2];
    const int c = blockIdx.x, b = blockIdx.y;
    const int tid = threadIdx.x;
    const long bt = (long)b * TLEN + c * CHUNK + tid;

    float sv = spart[bt] + spart[BT + bt] + spart[2l * BT + bt] + spart[3l * BT + bt];
    s_ws[bt] = sv;
    float ev = __expf(sv);
    el[tid] = ev;
    // per-chunk e total: wave reduce (64) + 2-wave combine
    float r = ev;
    #pragma unroll
    for (int off = 1; off < 64; off <<= 1) r += __shfl_xor(r, off);
    if ((tid & 63) == 0) wred[tid >> 6] = r;
    __syncthreads();
    if (tid == 0) esum[b * NCHUNK + c] = wred[0] + wred[1];

    const _Float16* xb = xh + ((long)b * TLEN + c * CHUNK) * DIM;
    float a0 = 0.f, a1 = 0.f, a2 = 0.f, a3 = 0.f;
    for (int t = 0; t < CHUNK; ++t) {
        h4 xv = *(const h4*)(xb + (long)t * DIM + tid * 4);
        float wgt = el[t];
        a0 += wgt * (float)xv[0];
        a1 += wgt * (float)xv[1];
        a2 += wgt * (float)xv[2];
        a3 += wgt * (float)xv[3];
    }
    float4 o = {a0, a1, a2, a3};
    ((float4*)(csum + ((long)(b * NCHUNK + c)) * DIM))[tid] = o;
}

// ---------------------------------------------------------------------------
// Kernel 3: context with folded exclusive prefix (chunk_scan deleted).
// Per (c,b) block: prefix a[d] = sum_{c'<c} csum[b,c',d] (L2-hot, ~64KB avg),
// den0 = sum_{c'<c} esum[b,c']; then stream
// out[t,:] = (a + running e*x) / (den0 + running e).
// FP16X=1 reads fp16 xh (only safe when xh lives in d_ws, not d_out).
// ---------------------------------------------------------------------------
template <int FP16X>
__global__ __launch_bounds__(128) void context_kernel(
    const float* __restrict__ x, const _Float16* __restrict__ xh,
    const float* __restrict__ s_ws, const float* __restrict__ csum,
    const float* __restrict__ esum, float* __restrict__ out)
{
    __shared__ float el[CHUNK];
    const int c = blockIdx.x, b = blockIdx.y;
    const int tid = threadIdx.x;
    const long rowbase = (long)b * TLEN + c * CHUNK;

    el[tid] = __expf(s_ws[rowbase + tid]);
    __syncthreads();

    // exclusive prefixes over chunks c' < c
    float a0 = 0.f, a1 = 0.f, a2 = 0.f, a3 = 0.f, den = 0.f;
    for (int cp = 0; cp < c; ++cp) {
        float4 v = ((const float4*)(csum + (long)(b * NCHUNK + cp) * DIM))[tid];
        a0 += v.x; a1 += v.y; a2 += v.z; a3 += v.w;
    }
    #pragma unroll 8
    for (int cp = 0; cp < NCHUNK; ++cp) {
        float v = esum[b * NCHUNK + cp];
        den += (cp < c) ? v : 0.f;
    }

    float4* ob = (float4*)(out + rowbase * DIM);
    for (int t = 0; t < CHUNK; ++t) {
        float xv0, xv1, xv2, xv3;
        if (FP16X) {
            h4 hv = *(const h4*)(xh + (rowbase + t) * DIM + tid * 4);
            xv0 = (float)hv[0]; xv1 = (float)hv[1];
            xv2 = (float)hv[2]; xv3 = (float)hv[3];
        } else {
            float4 fv = ((const float4*)(x + (rowbase + t) * DIM))[tid];
            xv0 = fv.x; xv1 = fv.y; xv2 = fv.z; xv3 = fv.w;
        }
        float wv = el[t];
        den += wv;
        a0 += wv * xv0; a1 += wv * xv1;
        a2 += wv * xv2; a3 += wv * xv3;
        float inv = __fdividef(1.0f, den);
        float4 o = {a0 * inv, a1 * inv, a2 * inv, a3 * inv};
        ob[t * (DIM / 4) + tid] = o;
    }
}

// ---------------------------------------------------------------------------
extern "C" void kernel_launch(void* const* d_in, const int* in_sizes, int n_in,
                              void* d_out, int out_size, void* d_ws, size_t ws_size,
                              hipStream_t stream)
{
    const float* x  = (const float*)d_in[0];   // [4,8192,512]
    const float* W1 = (const float*)d_in[1];   // [512,512] row-major [e][d]
    const float* b1 = (const float*)d_in[2];   // [512]
    const float* w2 = (const float*)d_in[3];   // [512]
    // d_in[4] = b2 scalar: softmax shift-invariant, unused.
    float* out = (float*)d_out;

    float* ws   = (float*)d_ws;
    float* s_ws = ws;                              // [32768]
    float* csum = ws + BT;                         // [131072]
    float* esum = ws + BT + 4 * NCHUNK * DIM;      // [256]
    const long ws_base_floats = BT + 4 * NCHUNK * DIM + 256;   // 164096

    // spart always in d_out scratch at 48 MB (consumed by chunk_sum
    // before context overwrites d_out with the real output).
    float* spart = out + 12l * 1024 * 1024;        // [4][32768] floats

    // fp16 operands: prefer d_ws (no aliasing with out -> context may read
    // fp16). Fallback: d_out low region (R5-benched layout, context reads
    // fp32 x).
    const size_t need = (size_t)ws_base_floats * 4
                      + ((size_t)BT * DIM + (size_t)DIM * DIM) * 2;
    const bool big_ws = ws_size >= need;

    _Float16* xh;
    _Float16* wh;
    if (big_ws) {
        xh = (_Float16*)(ws + ws_base_floats);
        wh = xh + (long)BT * DIM;
    } else {
        xh = (_Float16*)d_out;
        wh = xh + (long)BT * DIM;
    }

    const long total4 = ((long)BT * DIM + (long)DIM * DIM) / 4;
    const int convBlocks = (int)((total4 + 255) / 256);

    convert_kernel<<<convBlocks, 256, 0, stream>>>(x, W1, xh, wh);
    score_mfma_kernel<<<(BT / BM) * 4, 256, 0, stream>>>(xh, wh, b1, w2, spart);
    chunk_sum_kernel<<<dim3(NCHUNK, BATCH), 128, 0, stream>>>(xh, spart, s_ws, csum, esum);
    if (big_ws)
        context_kernel<1><<<dim3(NCHUNK, BATCH), 128, 0, stream>>>(x, xh, s_ws, csum, esum, out);
    else
        context_kernel<0><<<dim3(NCHUNK, BATCH), 128, 0, stream>>>(x, xh, s_ws, csum, esum, out);
}

// Round 11
// 79.236 us; speedup vs baseline: 1.4758x; 1.1273x over previous
//
#include <hip/hip_runtime.h>
#include <hip/hip_bf16.h>
#include <math.h>

// Problem constants
#define BATCH 4
#define TLEN 8192
#define BT 32768      // BATCH*TLEN
#define DIM 512
#define CHUNK 128     // t per chunk
#define NCHUNK 64     // TLEN / CHUNK

// score GEMM tile
#define BM 128
#define BN 128
#define BK 32

typedef _Float16 h8 __attribute__((ext_vector_type(8)));
typedef _Float16 h4 __attribute__((ext_vector_type(4)));
typedef float f4 __attribute__((ext_vector_type(4)));

__device__ __forceinline__ void gload_lds16(const _Float16* g, _Float16* l) {
    __builtin_amdgcn_global_load_lds(
        (const __attribute__((address_space(1))) void*)g,
        (__attribute__((address_space(3))) void*)l, 16, 0, 0);
}

// fast tanh: 1 - 2/(e^{2z}+1). |err| ~1e-6; saturates correctly at +-1.
__device__ __forceinline__ float fast_tanh(float z) {
    float u = __expf(2.0f * z);
    return 1.0f - __fdividef(2.0f, u + 1.0f);
}

// ---------------------------------------------------------------------------
// Kernel 0: convert x (fp32) and W1 (fp32) to fp16 into the given buffers.
// ---------------------------------------------------------------------------
__global__ __launch_bounds__(256) void convert_kernel(
    const float* __restrict__ x, const float* __restrict__ W1,
    _Float16* __restrict__ xh, _Float16* __restrict__ wh)
{
    const long i = (long)blockIdx.x * 256 + threadIdx.x;   // float4 index
    const long XD4 = (long)BT * DIM / 4;
    const long total4 = XD4 + (long)DIM * DIM / 4;
    if (i >= total4) return;
    float4 v;
    _Float16* dst;
    long j;
    if (i < XD4) { v = ((const float4*)x)[i];        dst = xh; j = i; }
    else         { v = ((const float4*)W1)[i - XD4]; dst = wh; j = i - XD4; }
    h4 o = { (_Float16)v.x, (_Float16)v.y, (_Float16)v.z, (_Float16)v.w };
    *(h4*)(dst + j * 4) = o;
}

// ---------------------------------------------------------------------------
// Kernel 1: score GEMM (R5-benched: 2-buffer counted-vmcnt pipeline).
// Per K-step: STAGE(s+1) -> vmcnt(4) -> barrier -> ds_read+MFMA ->
// lgkmcnt(0) -> barrier.
// ---------------------------------------------------------------------------
__global__ __launch_bounds__(256, 4) void score_mfma_kernel(
    const _Float16* __restrict__ xh, const _Float16* __restrict__ wh,
    const float* __restrict__ b1, const float* __restrict__ w2,
    float* __restrict__ spart)
{
    __shared__ _Float16 Als[2][BM * BK];   // 2 x 8 KB
    __shared__ _Float16 Bls[2][BM * BK];   // 2 x 8 KB
    __shared__ float sred[2][BM];          // 1 KB

    // bijective XCD-chunked swizzle over 1024 blocks (1024 % 8 == 0)
    const int orig = blockIdx.x;
    const int wid  = (orig & 7) * 128 + (orig >> 3);
    const int bt = wid >> 2, be = wid & 3;
    const long trow0 = (long)bt * BM;
    const int  ecol0 = be * BN;

    const int tid  = threadIdx.x;
    const int lane = tid & 63;
    const int w    = tid >> 6;       // 0..3
    const int wr   = w >> 1;         // t-half of tile
    const int wc   = w & 1;          // e-half of tile
    const int l15  = lane & 15;
    const int lg   = lane >> 4;      // 0..3

    // staging: wave w covers rows [w*32, w*32+32), 8 rows per 1KB issue pair.
    // source 16B-group = (lane&3) ^ (srow&3)  (involution; read applies same)
    const int srow = w * 32 + (lane >> 2);
    const int skof = ((lane & 3) ^ (srow & 3)) * 8;
    const _Float16* ga = xh + (trow0 + srow) * DIM + skof;
    const _Float16* gb = wh + (long)(ecol0 + srow) * DIM + skof;
    _Float16* laA0 = &Als[0][w * 1024];
    _Float16* laB0 = &Bls[0][w * 1024];
    _Float16* laA1 = &Als[1][w * 1024];
    _Float16* laB1 = &Bls[1][w * 1024];

    // frag-read swizzled k-offset: constant per lane (row&3 == l15&3)
    const int koff = (lg ^ (l15 & 3)) * 8;

    // preload epilogue operands BEFORE the pipeline so loop vmcnt is exact
    float b1v[4], w2v[4];
    #pragma unroll
    for (int n = 0; n < 4; ++n) {
        int e = ecol0 + wc * 64 + n * 16 + l15;
        b1v[n] = b1[e];
        w2v[n] = w2[e];
    }
    asm volatile("s_waitcnt vmcnt(0)" ::: "memory");

    f4 acc[4][4];
    #pragma unroll
    for (int m = 0; m < 4; ++m)
        #pragma unroll
        for (int n = 0; n < 4; ++n) acc[m][n] = (f4){0.f, 0.f, 0.f, 0.f};

#define STAGE(A_, B_, k0_) {                         \
    gload_lds16(ga + (k0_),            (A_));        \
    gload_lds16(ga + 16 * DIM + (k0_), (A_) + 512);  \
    gload_lds16(gb + (k0_),            (B_));        \
    gload_lds16(gb + 16 * DIM + (k0_), (B_) + 512);  }

#define COMPUTE(bsel_) {                                                      \
    h8 afr[4], bfr[4];                                                        \
    _Pragma("unroll")                                                         \
    for (int m = 0; m < 4; ++m)                                               \
        afr[m] = *(const h8*)&Als[bsel_][(wr * 64 + m * 16 + l15) * BK + koff]; \
    _Pragma("unroll")                                                         \
    for (int n = 0; n < 4; ++n)                                               \
        bfr[n] = *(const h8*)&Bls[bsel_][(wc * 64 + n * 16 + l15) * BK + koff]; \
    _Pragma("unroll")                                                         \
    for (int m = 0; m < 4; ++m)                                               \
        _Pragma("unroll")                                                     \
        for (int n = 0; n < 4; ++n)                                           \
            acc[m][n] = __builtin_amdgcn_mfma_f32_16x16x32_f16(               \
                afr[m], bfr[n], acc[m][n], 0, 0, 0);                          }

    STAGE(laA0, laB0, 0);                          // stage 0 in flight (4)
    #pragma unroll 2
    for (int s = 0; s < 15; ++s) {
        // issue stage s+1 -> 8 outstanding; vmcnt(4) waits only stage s
        if (s & 1) { STAGE(laA0, laB0, (s + 1) * BK); }
        else       { STAGE(laA1, laB1, (s + 1) * BK); }
        asm volatile("s_waitcnt vmcnt(4)" ::: "memory");
        __builtin_amdgcn_s_barrier();
        if (s & 1) { COMPUTE(1); } else { COMPUTE(0); }
        asm volatile("s_waitcnt lgkmcnt(0)" ::: "memory");  // reads done
        __builtin_amdgcn_s_barrier();              // buffer s&1 now restageable
    }
    asm volatile("s_waitcnt vmcnt(0)" ::: "memory");   // drain stage 15
    __builtin_amdgcn_s_barrier();
    COMPUTE(1);                                    // s=15 -> buffer 1

    // epilogue: p = sum over this lane's 4 e's of w2*tanh(h + b1)
    float pp[4][4];
    #pragma unroll
    for (int m = 0; m < 4; ++m)
        #pragma unroll
        for (int i = 0; i < 4; ++i) {
            float p = 0.f;
            #pragma unroll
            for (int n = 0; n < 4; ++n)
                p += w2v[n] * fast_tanh(acc[m][n][i] + b1v[n]);
            pp[m][i] = p;
        }
    // reduce across the 16 e-lanes of each lane-group
    #pragma unroll
    for (int off = 1; off < 16; off <<= 1)
        #pragma unroll
        for (int m = 0; m < 4; ++m)
            #pragma unroll
            for (int i = 0; i < 4; ++i)
                pp[m][i] += __shfl_xor(pp[m][i], off);
    __syncthreads();
    if (l15 == 0) {
        #pragma unroll
        for (int m = 0; m < 4; ++m)
            #pragma unroll
            for (int i = 0; i < 4; ++i)
                sred[wc][wr * 64 + m * 16 + lg * 4 + i] = pp[m][i];
    }
    __syncthreads();
    if (tid < BM)
        spart[(long)be * BT + trow0 + tid] = sred[0][tid] + sred[1][tid];
}

// ---------------------------------------------------------------------------
// Kernel 2: chunk_sum (R5-benched). s[t] = sum_be spart[be][t] (-> ws),
// e[t] = exp(s[t]); csum[b,c,d] = sum_t e[t]*xh[t,d]; esum[b,c] = sum_t e[t].
// No global max: softmax shift-invariant, |s| <= ||w2||_1 ~ 28 (no overflow).
// ---------------------------------------------------------------------------
__global__ __launch_bounds__(128) void chunk_sum_kernel(
    const _Float16* __restrict__ xh, const float* __restrict__ spart,
    float* __restrict__ s_ws, float* __restrict__ csum,
    float* __restrict__ esum)
{
    __shared__ float el[CHUNK];
    __shared__ float wred[2];
    const int c = blockIdx.x, b = blockIdx.y;
    const int tid = threadIdx.x;
    const long bt = (long)b * TLEN + c * CHUNK + tid;

    float sv = spart[bt] + spart[BT + bt] + spart[2l * BT + bt] + spart[3l * BT + bt];
    s_ws[bt] = sv;
    float ev = __expf(sv);
    el[tid] = ev;
    // per-chunk e total: wave reduce (64) + 2-wave combine
    float r = ev;
    #pragma unroll
    for (int off = 1; off < 64; off <<= 1) r += __shfl_xor(r, off);
    if ((tid & 63) == 0) wred[tid >> 6] = r;
    __syncthreads();
    if (tid == 0) esum[b * NCHUNK + c] = wred[0] + wred[1];

    const _Float16* xb = xh + ((long)b * TLEN + c * CHUNK) * DIM;
    float a0 = 0.f, a1 = 0.f, a2 = 0.f, a3 = 0.f;
    for (int t = 0; t < CHUNK; ++t) {
        h4 xv = *(const h4*)(xb + (long)t * DIM + tid * 4);
        float wgt = el[t];
        a0 += wgt * (float)xv[0];
        a1 += wgt * (float)xv[1];
        a2 += wgt * (float)xv[2];
        a3 += wgt * (float)xv[3];
    }
    float4 o = {a0, a1, a2, a3};
    ((float4*)(csum + ((long)(b * NCHUNK + c)) * DIM))[tid] = o;
}

// ---------------------------------------------------------------------------
// Kernel 3: chunk_scan (R5-benched). Per b: exclusive scan csum over c
// (512 lanes) and exclusive scan esum over c (one wave, shfl scan).
// ---------------------------------------------------------------------------
__global__ __launch_bounds__(576) void chunk_scan_kernel(
    float* __restrict__ csum, float* __restrict__ esum)
{
    const int b = blockIdx.x;
    const int tid = threadIdx.x;
    if (tid < 512) {
        const int d = tid;
        float run = 0.f;
        #pragma unroll 8
        for (int c = 0; c < NCHUNK; ++c) {
            float* p = csum + ((long)(b * NCHUNK + c)) * DIM + d;
            float v = *p;
            *p = run;
            run += v;
        }
    } else {
        const int lane = tid - 512;          // 0..63 == chunk id
        float v = esum[b * NCHUNK + lane];
        const float own = v;
        #pragma unroll
        for (int off = 1; off < 64; off <<= 1) {
            float u = __shfl_up(v, off);
            if (lane >= off) v += u;
        }
        esum[b * NCHUNK + lane] = v - own;   // exclusive prefix
    }
}

// ---------------------------------------------------------------------------
// Kernel 4: context (R5 structure; ONLY delta vs R5 = optional fp16 x reads).
// out[b,t,d] = (csum_excl + running e*x) / (den_excl + running e).
// FP16X=1 reads fp16 xh (safe only when xh lives in d_ws, not d_out).
// ---------------------------------------------------------------------------
template <int FP16X>
__global__ __launch_bounds__(128) void context_kernel(
    const float* __restrict__ x, const _Float16* __restrict__ xh,
    const float* __restrict__ s_ws, const float* __restrict__ esum,
    const float* __restrict__ csum, float* __restrict__ out)
{
    __shared__ float el[CHUNK];
    const int c = blockIdx.x, b = blockIdx.y;
    const int tid = threadIdx.x;
    const long rowbase = (long)b * TLEN + c * CHUNK;
    el[tid] = __expf(s_ws[rowbase + tid]);
    __syncthreads();
    float dacc = esum[b * NCHUNK + c];       // exclusive den prefix
    float4* ob = (float4*)(out + rowbase * DIM);
    float4 acc = ((const float4*)(csum + ((long)(b * NCHUNK + c)) * DIM))[tid];
    for (int t = 0; t < CHUNK; ++t) {
        float xv0, xv1, xv2, xv3;
        if (FP16X) {
            h4 hv = *(const h4*)(xh + (rowbase + t) * DIM + tid * 4);
            xv0 = (float)hv[0]; xv1 = (float)hv[1];
            xv2 = (float)hv[2]; xv3 = (float)hv[3];
        } else {
            float4 fv = ((const float4*)(x + (rowbase + t) * DIM))[tid];
            xv0 = fv.x; xv1 = fv.y; xv2 = fv.z; xv3 = fv.w;
        }
        float wv = el[t];
        dacc += wv;
        acc.x += wv * xv0; acc.y += wv * xv1;
        acc.z += wv * xv2; acc.w += wv * xv3;
        float inv = __fdividef(1.0f, dacc);
        float4 o = {acc.x * inv, acc.y * inv, acc.z * inv, acc.w * inv};
        ob[t * (DIM / 4) + tid] = o;
    }
}

// ---------------------------------------------------------------------------
extern "C" void kernel_launch(void* const* d_in, const int* in_sizes, int n_in,
                              void* d_out, int out_size, void* d_ws, size_t ws_size,
                              hipStream_t stream)
{
    const float* x  = (const float*)d_in[0];   // [4,8192,512]
    const float* W1 = (const float*)d_in[1];   // [512,512] row-major [e][d]
    const float* b1 = (const float*)d_in[2];   // [512]
    const float* w2 = (const float*)d_in[3];   // [512]
    // d_in[4] = b2 scalar: softmax shift-invariant, unused.
    float* out = (float*)d_out;

    float* ws   = (float*)d_ws;
    float* s_ws = ws;                              // [32768]
    float* csum = ws + BT;                         // [131072]
    float* esum = ws + BT + 4 * NCHUNK * DIM;      // [256]
    const long ws_base_floats = BT + 4 * NCHUNK * DIM + 256;   // 164096

    // spart in d_out scratch at 48 MB (consumed by chunk_sum before
    // context overwrites d_out with the real output).
    float* spart = out + 12l * 1024 * 1024;        // [4][32768] floats

    // fp16 operands: prefer d_ws (no aliasing with out -> context may read
    // fp16). Fallback: d_out low region (R5-benched layout, context reads
    // fp32 x).
    const size_t need = (size_t)ws_base_floats * 4
                      + ((size_t)BT * DIM + (size_t)DIM * DIM) * 2;
    const bool big_ws = ws_size >= need;

    _Float16* xh;
    _Float16* wh;
    if (big_ws) {
        xh = (_Float16*)(ws + ws_base_floats);
        wh = xh + (long)BT * DIM;
    } else {
        xh = (_Float16*)d_out;
        wh = xh + (long)BT * DIM;
    }

    const long total4 = ((long)BT * DIM + (long)DIM * DIM) / 4;
    const int convBlocks = (int)((total4 + 255) / 256);

    convert_kernel<<<convBlocks, 256, 0, stream>>>(x, W1, xh, wh);
    score_mfma_kernel<<<(BT / BM) * 4, 256, 0, stream>>>(xh, wh, b1, w2, spart);
    chunk_sum_kernel<<<dim3(NCHUNK, BATCH), 128, 0, stream>>>(xh, spart, s_ws, csum, esum);
    chunk_scan_kernel<<<BATCH, 576, 0, stream>>>(csum, esum);
    if (big_ws)
        context_kernel<1><<<dim3(NCHUNK, BATCH), 128, 0, stream>>>(x, xh, s_ws, esum, csum, out);
    else
        context_kernel<0><<<dim3(NCHUNK, BATCH), 128, 0, stream>>>(x, xh, s_ws, esum, csum, out);
}